// Round 10
// baseline (1025.506 us; speedup 1.0000x reference)
//
#include <hip/hip_runtime.h>

typedef unsigned int u32;

static __device__ __forceinline__ float sigf (float x){ return 1.0f/(1.0f+__expf(-x)); }
static __device__ __forceinline__ float tanh_(float x){ return 2.0f/(1.0f+__expf(-2.0f*x)) - 1.0f; }

#define NM 2730            // 273*10 distinct (t, j=b%10) rows
#define N_O0 878080        // 245*128*28

static __device__ __forceinline__ int dot4(u32 a, u32 b, int acc){
#if __has_builtin(__builtin_amdgcn_sdot4)
  return __builtin_amdgcn_sdot4((int)a, (int)b, acc, false);
#else
  int s = acc;
  #pragma unroll
  for(int i=0;i<4;i++){
    int av = (int)((signed char)((a >> (8*i)) & 0xffu));
    int bv = (int)((signed char)((b >> (8*i)) & 0xffu));
    s += av*bv;
  }
  return s;
#endif
}

// ---- prepall: ES (block 0) + int8 pack w/ own rowmax (blocks 1..1024)
// + transposes (blocks 1025..4726) + flag zero (block 1). One launch,
// no internal dependencies. ----
__global__ __launch_bounds__(256) void k_prepall(
    const float* __restrict__ x,
    const float* __restrict__ alpha, const float* __restrict__ gamma,
    const float* __restrict__ iseas,
    const float* __restrict__ wi0, const float* __restrict__ wi1,
    const float* __restrict__ wi2, const float* __restrict__ wi3,
    const float* __restrict__ lw,  const float* __restrict__ sw,
    const float* __restrict__ h0, const float* __restrict__ h1,
    const float* __restrict__ h2, const float* __restrict__ h3,
    float* __restrict__ xT,  float* __restrict__ wT0, float* __restrict__ wT1,
    float* __restrict__ wT2, float* __restrict__ wT3,
    float* __restrict__ lwT, float* __restrict__ swT,
    float* __restrict__ zsc, u32* __restrict__ W8,
    float* __restrict__ ST, float* __restrict__ lvlT,
    u32* __restrict__ flags){
  __shared__ float xs[128*61];               // 31.2 KB chunk stage (ES only)
  const int tid = threadIdx.x;
  const int bid = blockIdx.x;
  if(bid == 0){
    // ---- ES scan: 5 chunks of 60 timesteps staged through LDS ----
    int b = tid;
    float a=0.f, g=0.f, lvl=0.f;
    float q0=0,q1=0,q2=0,q3=0,q4=0,q5=0,q6=0;
    if(tid < 128){
      a = sigf(alpha[b]);
      g = sigf(gamma[b]);
      float S0[7];
      #pragma unroll
      for(int i=0;i<7;i++){ S0[i] = __expf(iseas[b*7+i]); ST[i*128+b] = S0[i]; }
      ST[7*128+b] = S0[0];
      q0=S0[1];q1=S0[2];q2=S0[3];q3=S0[4];q4=S0[5];q5=S0[6];q6=S0[0];
      lvl = 0.f; // set from chunk 0
      (void)lvl;
    }
    for(int c=0;c<5;c++){
      __syncthreads();
      for(int i=tid; i<128*60; i+=256){
        int bb = i/60, tt = i - bb*60;
        xs[bb*61 + tt] = x[bb*300 + c*60 + tt];
      }
      __syncthreads();
      if(tid < 128){
        int tt0 = 0;
        if(c == 0){
          lvl = xs[b*61] / q6;   // q6 currently S0[0]... careful: use ST
          // (q6 == S0[0] at this point, pre-rotation)
          lvlT[b] = lvl;
          tt0 = 1;
        }
        for(int tt=tt0; tt<60; tt++){
          int t = c*60 + tt;
          float xt = xs[b*61 + tt];
          float s  = q0;
          lvl = a*(xt/s) + (1.0f-a)*lvl;
          float sn = g*(xt/lvl) + (1.0f-g)*s;
          q0=q1;q1=q2;q2=q3;q3=q4;q4=q5;q5=q6;q6=sn;
          lvlT[t*128+b]   = lvl;
          ST[(t+7)*128+b] = sn;
        }
      }
    }
    return;
  }
  if(bid <= 1024){
    // ---- pack: 4 waves/block, one (layer,row) per wave ----
    if(bid == 1 && tid < 4) flags[tid] = 0u;   // zero layer flags
    int gid  = (bid-1)*4 + (tid >> 6);         // 0..4095
    int lane = tid & 63;
    int l    = gid >> 10;
    int row  = gid & 1023;
    const float* W = (l==0)?h0:(l==1)?h1:(l==2)?h2:h3;
    float4 v = ((const float4*)(W + (size_t)row*256))[lane];
    float m = fmaxf(fmaxf(fabsf(v.x),fabsf(v.y)), fmaxf(fabsf(v.z),fabsf(v.w)));
    #pragma unroll
    for(int d=1; d<64; d<<=1) m = fmaxf(m, __shfl_xor(m, d));
    float zv = fmaxf(m, 1e-20f) * (1.0f/16129.0f);
    if(lane == 0) zsc[gid] = zv;
    float inv = 1.0f / (zv * 127.0f);
    u32 out = 0;
    {
      float vv[4] = {v.x, v.y, v.z, v.w};
      #pragma unroll
      for(int bq=0;bq<4;bq++){
        int q8 = max(-127, min(127, __float2int_rn(vv[bq] * inv)));
        out |= ((u32)(q8 & 0xff)) << (8*bq);
      }
    }
    int js = lane >> 4, q = (lane >> 2) & 3, dw = lane & 3;
    W8[(size_t)l*65536 + js*16384 + (row>>7)*2048 + q*512 + (row&127)*4 + dw] = out;
    return;
  }
  // ---- transposes: 947712 items ----
  int i = (bid-1025)*256 + tid;
  if(i < 38400){ int t=i>>7, b=i&127; xT[i] = x[b*300+t]; return; }
  i -= 38400;
  if(i < 50176){ int c=i/1024, r=i-c*1024; wT0[i] = wi0[r*49+c]; return; }
  i -= 50176;
  if(i < 262144){ int c=i>>10, r=i&1023; wT1[i] = wi1[r*256+c]; return; }
  i -= 262144;
  if(i < 262144){ int c=i>>10, r=i&1023; wT2[i] = wi2[r*256+c]; return; }
  i -= 262144;
  if(i < 262144){ int c=i>>10, r=i&1023; wT3[i] = wi3[r*256+c]; return; }
  i -= 262144;
  if(i < 65536){ int c=i>>8, r=i&255; lwT[i] = lw[r*256+c]; return; }
  i -= 65536;
  if(i < 7168){ int c=i/28, r=i-c*28; swT[i] = sw[r*256+c]; }
}

// ---- fused gemm + scan, one launch per layer.
// blocks 0..170: gemm (512 thr, 16 rows/block); release-atomicAdd flag.
// blocks 171..170+chains: champion v9 scan; waits once on flag==171.
// 171+60=231 blocks < 256 CUs -> all co-resident at any occupancy ->
// no deadlock; spin is one-shot (~10us) on <=60 WGs. ----
__global__ __launch_bounds__(512) void k_gs(
    const float* __restrict__ X,     // non-first input (Y of prev layer)
    const float* __restrict__ xT, const float* __restrict__ ST,
    const float* __restrict__ lvlT, const float* __restrict__ cats,
    const float* __restrict__ mp,
    const float* __restrict__ WT, const float* __restrict__ bias,
    float* __restrict__ Z,
    const u32* __restrict__ W8, const float* __restrict__ zsc,
    float* __restrict__ Y, const float* __restrict__ RES,
    u32* __restrict__ flag,
    int first, int chains, int d){
  __shared__ __align__(16) char arena[21504];  // 21 KB union
  const int tid = threadIdx.x;
  const int bid = blockIdx.x;
  if(bid < 171){
    // ---------------- gemm ----------------
    float* Xs = (float*)arena;                 // [16][256] or [16][52]
    const int m0 = bid*16;
    const int XSTR = first ? 52 : 256;
    if(first){
      for(int idx=tid; idx<16*49; idx+=512){
        int p = idx/49, f = idx - p*49;
        int m = m0+p;
        float v = 0.f;
        if(m < NM){
          int tt = m/10, jj = m - (m/10)*10;
          if(f < 28){
            int c = tt + f;
            v = xT[c*128+jj] / ST[c*128+jj] / lvlT[(tt+27)*128+jj];
          } else if(f < 48){
            v = cats[jj*20 + (f-28)];
          } else {
            v = mp[0];
          }
        }
        Xs[p*XSTR + f] = v;
      }
    } else {
      for(int idx=tid; idx<16*256; idx+=512){
        int p = idx >> 8, c = idx & 255;
        int m = m0+p;
        Xs[p*XSTR + c] = (m < NM) ? X[(size_t)m*256 + c] : 0.f;
      }
    }
    __syncthreads();
    float a0[16], a1[16];
    {
      float b0 = bias[tid], b1 = bias[tid+512];
      #pragma unroll
      for(int p=0;p<16;p++){ a0[p]=b0; a1[p]=b1; }
    }
    const int K = first ? 49 : 256;
    #pragma unroll 4
    for(int f=0; f<K; f++){
      float w0 = WT[f*1024 + tid];
      float w1 = WT[f*1024 + tid + 512];
      #pragma unroll
      for(int p=0;p<16;p++){
        float xv = Xs[p*XSTR + f];
        a0[p] += w0*xv; a1[p] += w1*xv;
      }
    }
    for(int p=0;p<16;p++){
      int m = m0+p;
      if(m < NM){
        float* zb = Z + (size_t)m*1024;
        zb[tid] = a0[p]; zb[tid+512] = a1[p];
      }
    }
    __syncthreads();
    __threadfence();
    if(tid == 0)
      __hip_atomic_fetch_add(flag, 1u, __ATOMIC_RELEASE, __HIP_MEMORY_SCOPE_AGENT);
    return;
  }
  // ---------------- scan (champion v9) ----------------
  const int chain = bid - 171;
  if(chain >= chains) return;
  u32*   h8 = (u32*)arena;                     // 256 B
  int*   zp = (int*)(arena + 256);             // 16 KB [4][1024]
  float* sc = (float*)(arena + 256 + 16384);   // 4 KB
  // wait once for gemm completion
  if(tid == 0){
    while(__hip_atomic_load(flag, __ATOMIC_RELAXED, __HIP_MEMORY_SCOPE_AGENT) < 171u)
      __builtin_amdgcn_s_sleep(8);
  }
  __syncthreads();
  __builtin_amdgcn_fence(__ATOMIC_ACQUIRE, "agent");
  const int j = chain % 10;
  const int r = chain / 10;
  const int ns = (273 - r + d - 1)/d;
  const int kg = tid & 127;
  const int js = tid >> 7;
  const uint4* Wb = (const uint4*)W8 + (size_t)js*4096 + kg;
  const uint4* hq = (const uint4*)h8 + js*4;

  for(int i=tid;i<1024;i+=512) sc[i] = zsc[i];
  if(tid < 64) h8[tid] = 0u;
  float cst = 0.0f;
  __syncthreads();

  int t = r;
  for(int s=0; s<ns; s++, t+=d){
    const size_t row = (size_t)(t*10 + j);
    float zv0=0.f, zv1=0.f, zv2=0.f, zv3=0.f, rv=0.f;
    if(tid < 256){                       // prefetch (consumed after barrier)
      const float* zb = Z + row*1024;
      zv0 = zb[tid]; zv1 = zb[tid+256]; zv2 = zb[tid+512]; zv3 = zb[tid+768];
      if(RES) rv = RES[row*256 + tid];
    }
    int a0=0,a1=0,a2=0,a3=0,a4=0,a5=0,a6=0,a7=0;
    #pragma unroll
    for(int q=0;q<4;q++){
      uint4 h4 = hq[q];                  // broadcast: 16 h int8
      #pragma unroll
      for(int rr=0;rr<8;rr++){
        uint4 w = Wb[rr*512 + q*128];    // L2 stream (the floor)
        int* ap = (rr==0)?&a0:(rr==1)?&a1:(rr==2)?&a2:(rr==3)?&a3:
                  (rr==4)?&a4:(rr==5)?&a5:(rr==6)?&a6:&a7;
        int acc = *ap;
        acc = dot4(w.x, h4.x, acc);
        acc = dot4(w.y, h4.y, acc);
        acc = dot4(w.z, h4.z, acc);
        acc = dot4(w.w, h4.w, acc);
        *ap = acc;
      }
    }
    zp[js*1024 +       kg] = a0;
    zp[js*1024 + 128 + kg] = a1;
    zp[js*1024 + 256 + kg] = a2;
    zp[js*1024 + 384 + kg] = a3;
    zp[js*1024 + 512 + kg] = a4;
    zp[js*1024 + 640 + kg] = a5;
    zp[js*1024 + 768 + kg] = a6;
    zp[js*1024 + 896 + kg] = a7;
    __syncthreads();
    if(tid < 256){
      const int u = tid;
      int si = zp[u]     + zp[1024+u]     + zp[2048+u]     + zp[3072+u];
      int sf = zp[u+256] + zp[1024+u+256] + zp[2048+u+256] + zp[3072+u+256];
      int sg = zp[u+512] + zp[1024+u+512] + zp[2048+u+512] + zp[3072+u+512];
      int so = zp[u+768] + zp[1024+u+768] + zp[2048+u+768] + zp[3072+u+768];
      float zi = zv0 + sc[u]     * (float)si;
      float zf = zv1 + sc[u+256] * (float)sf;
      float zg = zv2 + sc[u+512] * (float)sg;
      float zo = zv3 + sc[u+768] * (float)so;
      float c  = sigf(zf)*cst + sigf(zi)*tanh_(zg);
      float h  = sigf(zo)*tanh_(c);
      cst = c;
      int hqi = __float2int_rn(h * 127.0f);
      hqi = max(-127, min(127, hqi));
      ((signed char*)h8)[u] = (signed char)hqi;
      Y[row*256 + u] = h + rv;
    }
    // LDS-only fence: don't drain vmcnt; Y store drains under next step
    asm volatile("s_waitcnt lgkmcnt(0)\n\ts_barrier" ::: "memory");
  }
}

// ---- head (blocks 0..341) + actual_values (342..586) + hav (587) ----
__global__ __launch_bounds__(256) void k_headav(const float* __restrict__ Y4,
    const float* __restrict__ LWT, const float* __restrict__ lb,
    const float* __restrict__ SWT, const float* __restrict__ sb,
    const float* __restrict__ ST, const float* __restrict__ lvlT,
    const float* __restrict__ xT, const float* __restrict__ val,
    float* __restrict__ rnnS, float* __restrict__ out){
  __shared__ float arena[4224];                // 16.9 KB union
  const int tid = threadIdx.x;
  const int bid = blockIdx.x;
  if(bid < 342){
    float* v  = arena;                         // [8][256]
    float* h2 = arena + 2048;                  // [8][256]
    const int m0 = bid*8;
    for(int p=0;p<8;p++){
      int m = m0+p;
      v[p*256+tid] = (m<NM) ? Y4[m*256+tid] : 0.0f;
    }
    __syncthreads();
    float acc[8];
    float bz = lb[tid];
    #pragma unroll
    for(int p=0;p<8;p++) acc[p]=bz;
    #pragma unroll 4
    for(int f=0; f<256; f++){
      float w = LWT[f*256+tid];
      #pragma unroll
      for(int p=0;p<8;p++) acc[p] += w * v[p*256+f];
    }
    #pragma unroll
    for(int p=0;p<8;p++) h2[p*256+tid] = tanh_(acc[p]);
    __syncthreads();
    if(tid < 224){
      int o = tid % 28, p = tid / 28;
      int m = m0 + p;
      if(m < NM){
        float a = sb[o];
        for(int f=0; f<256; f++) a += SWT[f*28+o] * h2[p*256+f];
        rnnS[m*28 + o] = a;
      }
    }
    return;
  }
  if(bid < 587){                               // actual_values, t = bid-342
    float* av = arena;                         // [28][132] padded
    const int t = bid - 342;
    for(int i=tid; i<28*128; i+=256){
      int o = i >> 7, b = i & 127;
      int c = 28 + t + o;
      av[o*132 + b] = xT[c*128+b] / ST[c*128+b] / lvlT[(27+t)*128+b];
    }
    __syncthreads();
    for(int i=tid; i<3584; i+=256){
      int b = i/28, o = i - b*28;
      out[878080 + t*3584 + i] = av[o*132 + b];
    }
    return;
  }
  // hav + hav_norm
  for(int i=tid; i<3584; i+=256){
    int b = i/28, o = i%28;
    int col = (o < 21) ? (286+o) : (279+o);
    float Sm = ST[col*128 + b];
    float lv = lvlT[299*128 + b];
    out[2738176 + i] = val[i];
    out[2741760 + i] = val[i] / Sm / lv;
  }
}

// ---- bcast: rnn_out + prediction_values + holdout (coalesced stores) ----
__global__ __launch_bounds__(256) void k_bcast(
    const float* __restrict__ rnnS, const float* __restrict__ ST,
    const float* __restrict__ lvlT, float* __restrict__ out){
  for(int i0 = blockIdx.x*256 + threadIdx.x; i0 < 978432 + 3584; i0 += 1024*256){
    int i = i0;
    if(i < 978432){
      int t = i/3584; int rr = i - t*3584;
      int b = rr/28;  int o = rr - b*28;
      int j = b % 10;
      float a = rnnS[(t*10 + j)*28 + o];
      out[1759744 + i] = a;
      if(t < 245) out[i] = a;
    } else { i -= 978432;
      int b = i/28, o = i - (i/28)*28;
      int j = b % 10;
      float a = rnnS[(2720 + j)*28 + o];
      int col = (o < 21) ? (286+o) : (279+o);
      float hv = a * ST[col*128 + b] * lvlT[299*128 + b];
      out[1756160 + i] = (hv > 0.0f) ? hv : 0.0f;
    }
  }
}

extern "C" void kernel_launch(void* const* d_in, const int* in_sizes, int n_in,
                              void* d_out, int out_size, void* d_ws, size_t ws_size,
                              hipStream_t stream){
  (void)in_sizes; (void)n_in; (void)out_size; (void)ws_size;
  const float* x     = (const float*)d_in[0];
  const float* val   = (const float*)d_in[1];
  const float* alpha = (const float*)d_in[2];
  const float* gamma = (const float*)d_in[3];
  const float* iseas = (const float*)d_in[4];
  const float* cats  = (const float*)d_in[5];
  const float* mp    = (const float*)d_in[6];
  const float* Wih[4]  = {(const float*)d_in[7],  (const float*)d_in[10], (const float*)d_in[13], (const float*)d_in[16]};
  const float* Whh[4]  = {(const float*)d_in[8],  (const float*)d_in[11], (const float*)d_in[14], (const float*)d_in[17]};
  const float* bias[4] = {(const float*)d_in[9],  (const float*)d_in[12], (const float*)d_in[15], (const float*)d_in[18]};
  const float* linW  = (const float*)d_in[19];
  const float* linb  = (const float*)d_in[20];
  const float* scW   = (const float*)d_in[21];
  const float* scb   = (const float*)d_in[22];

  // ---- workspace layout ----
  float* Fw   = (float*)d_ws;
  float* ST   = Fw;                 // 39296
  float* lvlT = ST   + 39296;       // 38400
  float* xT   = lvlT + 38400;       // 38400
  float* xz   = xT   + 38400;       // 2795520
  float* yA   = xz   + 2795520;     // 698880
  float* yB   = yA   + 698880;      // 698880
  float* wihT[4];
  wihT[0] = yB + 698880;            // 50176
  wihT[1] = wihT[0] + 50176;        // 262144
  wihT[2] = wihT[1] + 262144;
  wihT[3] = wihT[2] + 262144;
  float* linWT = wihT[3] + 262144;  // 65536
  float* scT   = linWT + 65536;     // 7168
  float* zsc   = scT   + 7168;      // 4096
  u32*   W8all = (u32*)(zsc + 4096);// 262144 u32
  float* rnnS  = (float*)(W8all + 262144); // 76440
  u32*   flags = (u32*)(rnnS + 76440);     // 4

  // ---- 1: prepall (ES + pack + transposes + flag zero) ----
  k_prepall<<<4727, 256, 0, stream>>>(x, alpha, gamma, iseas,
      Wih[0], Wih[1], Wih[2], Wih[3], linW, scW,
      Whh[0], Whh[1], Whh[2], Whh[3],
      xT, wihT[0], wihT[1], wihT[2], wihT[3], linWT, scT,
      zsc, W8all, ST, lvlT, flags);

  // ---- 2-5: fused gemm+scan per layer ----
  const int    dlt[4]    = {1, 2, 2, 6};
  const int    chains[4] = {10, 20, 20, 60};
  const float* Xin[4]    = {nullptr, yA, yB, yA};
  float*       Yout[4]   = {yA, yB, yA, yA};
  for(int l=0;l<4;l++){
    k_gs<<<171 + chains[l], 512, 0, stream>>>(
        Xin[l], xT, ST, lvlT, cats, mp,
        wihT[l], bias[l], xz,
        W8all + l*65536, zsc + l*1024,
        Yout[l], (l==3) ? yB : (const float*)nullptr,
        flags + l, (l==0) ? 1 : 0, chains[l], dlt[l]);
  }

  // ---- 6: head + actual_values + hav ; 7: broadcast ----
  k_headav<<<588, 256, 0, stream>>>(yA, linWT, linb, scT, scb,
                                    ST, lvlT, xT, val, rnnS, (float*)d_out);
  k_bcast<<<1024, 256, 0, stream>>>(rnnS, ST, lvlT, (float*)d_out);
}

// Round 11
// 961.408 us; speedup vs baseline: 1.0667x; 1.0667x over previous
//
#include <hip/hip_runtime.h>

typedef unsigned int u32;

static __device__ __forceinline__ float sigf (float x){ return 1.0f/(1.0f+__expf(-x)); }
static __device__ __forceinline__ float tanh_(float x){ return 2.0f/(1.0f+__expf(-2.0f*x)) - 1.0f; }

#define NM 2730            // 273*10 distinct (t, j=b%10) rows
#define N_O0 878080        // 245*128*28

static __device__ __forceinline__ int dot4(u32 a, u32 b, int acc){
#if __has_builtin(__builtin_amdgcn_sdot4)
  return __builtin_amdgcn_sdot4((int)a, (int)b, acc, false);
#else
  int s = acc;
  #pragma unroll
  for(int i=0;i<4;i++){
    int av = (int)((signed char)((a >> (8*i)) & 0xffu));
    int bv = (int)((signed char)((b >> (8*i)) & 0xffu));
    s += av*bv;
  }
  return s;
#endif
}

// ---- fused prep: xT + 6 transposes + Whh row scales (R8 champion) ----
__global__ __launch_bounds__(256) void k_prep(
    const float* __restrict__ x,     float* __restrict__ xT,
    const float* __restrict__ wi0,   float* __restrict__ wT0,
    const float* __restrict__ wi1,   float* __restrict__ wT1,
    const float* __restrict__ wi2,   float* __restrict__ wT2,
    const float* __restrict__ wi3,   float* __restrict__ wT3,
    const float* __restrict__ lw,    float* __restrict__ lwT,
    const float* __restrict__ sw,    float* __restrict__ swT,
    const float* __restrict__ h0, const float* __restrict__ h1,
    const float* __restrict__ h2, const float* __restrict__ h3,
    float* __restrict__ zsc){
  int i = blockIdx.x*256 + threadIdx.x;
  if(i < 38400){                    // xT
    int t = i >> 7, b = i & 127;
    xT[i] = x[b*300 + t];
    return;
  }
  i -= 38400;
  if(i < 50176){ int c=i/1024, r=i-c*1024; wT0[i] = wi0[r*49 + c];  return; }
  i -= 50176;
  if(i < 262144){ int c=i>>10, r=i&1023; wT1[i] = wi1[r*256 + c];   return; }
  i -= 262144;
  if(i < 262144){ int c=i>>10, r=i&1023; wT2[i] = wi2[r*256 + c];   return; }
  i -= 262144;
  if(i < 262144){ int c=i>>10, r=i&1023; wT3[i] = wi3[r*256 + c];   return; }
  i -= 262144;
  if(i < 65536){ int c=i>>8, r=i&255; lwT[i] = lw[r*256 + c];       return; }
  i -= 65536;
  if(i < 7168){ int c=i/28, r=i-c*28; swT[i] = sw[r*256 + c];       return; }
  i -= 7168;
  if(i < 4096){                     // per-row absmax scale (int8)
    int l = i >> 10, r = i & 1023;
    const float* W = (l==0)?h0:(l==1)?h1:(l==2)?h2:h3;
    const float4* p = (const float4*)(W + (size_t)r*256);
    float m = 0.f;
    #pragma unroll 8
    for(int q=0;q<64;q++){
      float4 v = p[q];
      m = fmaxf(m, fmaxf(fmaxf(fabsf(v.x),fabsf(v.y)), fmaxf(fabsf(v.z),fabsf(v.w))));
    }
    zsc[i] = fmaxf(m, 1e-20f) * (1.0f/16129.0f);   // rowmax/(127*127)
  }
}

// ---- fused int8 pack (v9 uidx layout) + LDS-staged ES scan (R8) ----
__global__ __launch_bounds__(256) void k_packes(
    const float* __restrict__ h0, const float* __restrict__ h1,
    const float* __restrict__ h2, const float* __restrict__ h3,
    const float* __restrict__ zsc, u32* __restrict__ W8,
    const float* __restrict__ xT, const float* __restrict__ alpha,
    const float* __restrict__ gamma, const float* __restrict__ iseas,
    float* __restrict__ ST, float* __restrict__ lvlT){
  __shared__ float xs[128*301];              // 154 KB (pad 301: bank-spread)
  if(blockIdx.x < 1024){
    int i = blockIdx.x*256 + threadIdx.x;      // 0..262143
    int l = i >> 16;
    int uidx = i & 65535;
    int dw = uidx & 3;
    int kg = (uidx >> 2) & 127;
    int q  = (uidx >> 9) & 3;
    int rr = (uidx >> 11) & 7;
    int js = uidx >> 14;
    int row = rr*128 + kg;
    int k0  = js*64 + q*16 + dw*4;
    const float* W = (l==0)?h0:(l==1)?h1:(l==2)?h2:h3;
    float inv = 1.0f / (zsc[l*1024 + row] * 127.0f);
    u32 out = 0;
    #pragma unroll
    for(int b=0;b<4;b++){
      float v = W[(size_t)row*256 + k0 + b];
      int q8 = max(-127, min(127, __float2int_rn(v * inv)));
      out |= ((u32)(q8 & 0xff)) << (8*b);
    }
    W8[i] = out;
    return;
  }
  // ES scan block: stage xT -> LDS (coalesced), then 128-thread scan
  for(int i=threadIdx.x; i<38400; i+=256){
    int t = i >> 7, b = i & 127;
    xs[b*301 + t] = xT[i];
  }
  __syncthreads();
  int b = threadIdx.x;
  if(b >= 128) return;
  float a = sigf(alpha[b]);
  float g = sigf(gamma[b]);
  float S0[7];
  #pragma unroll
  for(int i=0;i<7;i++){ S0[i] = __expf(iseas[b*7+i]); ST[i*128+b] = S0[i]; }
  ST[7*128+b] = S0[0];
  float q0=S0[1],q1=S0[2],q2=S0[3],q3=S0[4],q4=S0[5],q5=S0[6],q6=S0[0];
  float lvl = xs[b*301]/S0[0];
  lvlT[b] = lvl;
  for(int t=1;t<300;t++){
    float xt = xs[b*301 + t];
    float s  = q0;
    lvl = a*(xt/s) + (1.0f-a)*lvl;
    float sn = g*(xt/lvl) + (1.0f-g)*s;
    q0=q1;q1=q2;q2=q3;q3=q4;q4=q5;q5=q6;q6=sn;
    lvlT[t*128+b]   = lvl;
    ST[(t+7)*128+b] = sn;
  }
}

// ---- gemm for layer 1: window_input built on the fly (R8) ----
__global__ __launch_bounds__(256) void k_gemm1(
    const float* __restrict__ xT, const float* __restrict__ ST,
    const float* __restrict__ lvlT, const float* __restrict__ cats,
    const float* __restrict__ mp,
    const float* __restrict__ WT,   // [49][1024] f32
    const float* __restrict__ bias, // [1024] f32
    float* __restrict__ Z){
  __shared__ float Xs[8][52];
  const int tid = threadIdx.x;
  const int m0 = blockIdx.x*8;
  for(int idx=tid; idx<8*49; idx+=256){
    int p = idx/49, f = idx - p*49;
    int m = m0+p;
    float v = 0.f;
    if(m < NM){
      int tt = m/10, jj = m - (m/10)*10;
      if(f < 28){
        int c = tt + f;
        v = xT[c*128 + jj] / ST[c*128 + jj] / lvlT[(tt+27)*128 + jj];
      } else if(f < 48){
        v = cats[jj*20 + (f-28)];
      } else {
        v = mp[0];
      }
    }
    Xs[p][f] = v;
  }
  __syncthreads();
  float acc0[8], acc1[8], acc2[8], acc3[8];
  {
    float b0 = bias[tid];
    float b1 = bias[tid+256];
    float b2 = bias[tid+512];
    float b3 = bias[tid+768];
    #pragma unroll
    for(int p=0;p<8;p++){ acc0[p]=b0; acc1[p]=b1; acc2[p]=b2; acc3[p]=b3; }
  }
  #pragma unroll 7
  for(int f=0; f<49; f++){
    float w0 = WT[f*1024 + tid      ];
    float w1 = WT[f*1024 + tid+256  ];
    float w2 = WT[f*1024 + tid+512  ];
    float w3 = WT[f*1024 + tid+768  ];
    #pragma unroll
    for(int p=0;p<8;p++){
      float xv = Xs[p][f];
      acc0[p] += w0*xv; acc1[p] += w1*xv; acc2[p] += w2*xv; acc3[p] += w3*xv;
    }
  }
  for(int p=0;p<8;p++){
    int m = m0+p;
    if(m < NM){
      float* zb = Z + m*1024 + tid;
      zb[0]=acc0[p]; zb[256]=acc1[p]; zb[512]=acc2[p]; zb[768]=acc3[p];
    }
  }
}

// ---- batched xz = X @ WihT + b (R8) ----
__global__ __launch_bounds__(256) void k_gemm(const float* __restrict__ X,
                                              const float* __restrict__ WT,   // [256][1024] f32
                                              const float* __restrict__ bias, // [1024] f32
                                              float* __restrict__ Z){
  __shared__ float Xs[8][256];
  const int tid = threadIdx.x;
  const int m0 = blockIdx.x*8;
  for(int p=0;p<8;p++){
    int m = m0+p;
    Xs[p][tid] = (m < NM) ? X[m*256+tid] : 0.0f;
  }
  __syncthreads();
  float acc0[8], acc1[8], acc2[8], acc3[8];
  {
    float b0 = bias[tid];
    float b1 = bias[tid+256];
    float b2 = bias[tid+512];
    float b3 = bias[tid+768];
    #pragma unroll
    for(int p=0;p<8;p++){ acc0[p]=b0; acc1[p]=b1; acc2[p]=b2; acc3[p]=b3; }
  }
  #pragma unroll 4
  for(int f=0; f<256; f++){
    float w0 = WT[f*1024 + tid      ];
    float w1 = WT[f*1024 + tid+256  ];
    float w2 = WT[f*1024 + tid+512  ];
    float w3 = WT[f*1024 + tid+768  ];
    #pragma unroll
    for(int p=0;p<8;p++){
      float xv = Xs[p][f];
      acc0[p] += w0*xv; acc1[p] += w1*xv; acc2[p] += w2*xv; acc3[p] += w3*xv;
    }
  }
  for(int p=0;p<8;p++){
    int m = m0+p;
    if(m < NM){
      float* zb = Z + m*1024 + tid;
      zb[0]=acc0[p]; zb[256]=acc1[p]; zb[512]=acc2[p]; zb[768]=acc3[p];
    }
  }
}

// ---- LSTM scan: CHAMPION v9 structure + idle-CU piggyback.
// Blocks 0..chains-1: unmodified champion scan (per-CU VMEM-return
// roofline: 256KB/step / 128B/cyc + gates = 2350cyc, verified).
// Blocks >= chains (layer-1 launch only, grid=256): actual_values
// t-tiles and hav — INDEPENDENT of the scan (need only ST/lvlT/xT/val
// from completed dispatches): no flags, no spin, free CUs. ----
__global__ __launch_bounds__(512) void k_scan8(
    const float* __restrict__ Z,
    const u32* __restrict__ W8,    // packed int8 weights (256 KB)
    const float* __restrict__ zsc, // [1024] per-row z scales
    float* __restrict__ Y,
    const float* __restrict__ RES,
    const float* __restrict__ xT, const float* __restrict__ ST,
    const float* __restrict__ lvlT, const float* __restrict__ val,
    float* __restrict__ out,
    int chains, int d){
  __shared__ __align__(16) char arena[21504];
  const int tid = threadIdx.x;
  const int bid = blockIdx.x;
  if(bid >= chains){
    // ---- piggyback on idle CUs ----
    const int t = bid - chains;          // 0..244 actual_values, 245 hav
    if(t < 245){
      float* av = (float*)arena;         // [28][132] padded tile
      for(int i=tid; i<28*128; i+=512){
        int o = i >> 7, b = i & 127;
        int c = 28 + t + o;
        av[o*132 + b] = xT[c*128+b] / ST[c*128+b] / lvlT[(27+t)*128+b];
      }
      __syncthreads();
      for(int i=tid; i<3584; i+=512){
        int b = i/28, o = i - b*28;
        out[878080 + t*3584 + i] = av[o*132 + b];
      }
    } else if(t == 245){
      for(int i=tid; i<3584; i+=512){
        int b = i/28, o = i%28;
        int col = (o < 21) ? (286+o) : (279+o);
        float Sm = ST[col*128 + b];
        float lv = lvlT[299*128 + b];
        out[2738176 + i] = val[i];
        out[2741760 + i] = val[i] / Sm / lv;
      }
    }
    return;
  }
  // ---- champion scan ----
  u32*   h8 = (u32*)arena;                   // 256 B
  int*   zp = (int*)(arena + 256);           // 16 KB [4][1024]
  float* sc = (float*)(arena + 256 + 16384); // 4 KB
  const int chain = bid;
  const int j = chain % 10;
  const int r = chain / 10;
  const int ns = (273 - r + d - 1)/d;
  const int kg = tid & 127;
  const int js = tid >> 7;
  const uint4* Wb = (const uint4*)W8 + (size_t)js*4096 + kg;
  const uint4* hq = (const uint4*)h8 + js*4;

  for(int i=tid;i<1024;i+=512) sc[i] = zsc[i];
  if(tid < 64) h8[tid] = 0u;
  float cst = 0.0f;
  __syncthreads();

  int t = r;
  for(int s=0; s<ns; s++, t+=d){
    const size_t row = (size_t)(t*10 + j);
    float zv0=0.f, zv1=0.f, zv2=0.f, zv3=0.f, rv=0.f;
    if(tid < 256){                       // prefetch (consumed after barrier)
      const float* zb = Z + row*1024;
      zv0 = zb[tid]; zv1 = zb[tid+256]; zv2 = zb[tid+512]; zv3 = zb[tid+768];
      if(RES) rv = RES[row*256 + tid];
    }
    int a0=0,a1=0,a2=0,a3=0,a4=0,a5=0,a6=0,a7=0;
    #pragma unroll
    for(int q=0;q<4;q++){
      uint4 h4 = hq[q];                  // broadcast: 16 h int8
      #pragma unroll
      for(int rr=0;rr<8;rr++){
        uint4 w = Wb[rr*512 + q*128];    // L2 stream (the roofline)
        int* ap = (rr==0)?&a0:(rr==1)?&a1:(rr==2)?&a2:(rr==3)?&a3:
                  (rr==4)?&a4:(rr==5)?&a5:(rr==6)?&a6:&a7;
        int acc = *ap;
        acc = dot4(w.x, h4.x, acc);
        acc = dot4(w.y, h4.y, acc);
        acc = dot4(w.z, h4.z, acc);
        acc = dot4(w.w, h4.w, acc);
        *ap = acc;
      }
    }
    zp[js*1024 +       kg] = a0;
    zp[js*1024 + 128 + kg] = a1;
    zp[js*1024 + 256 + kg] = a2;
    zp[js*1024 + 384 + kg] = a3;
    zp[js*1024 + 512 + kg] = a4;
    zp[js*1024 + 640 + kg] = a5;
    zp[js*1024 + 768 + kg] = a6;
    zp[js*1024 + 896 + kg] = a7;
    __syncthreads();
    if(tid < 256){
      const int u = tid;
      int si = zp[u]     + zp[1024+u]     + zp[2048+u]     + zp[3072+u];
      int sf = zp[u+256] + zp[1024+u+256] + zp[2048+u+256] + zp[3072+u+256];
      int sg = zp[u+512] + zp[1024+u+512] + zp[2048+u+512] + zp[3072+u+512];
      int so = zp[u+768] + zp[1024+u+768] + zp[2048+u+768] + zp[3072+u+768];
      float zi = zv0 + sc[u]     * (float)si;
      float zf = zv1 + sc[u+256] * (float)sf;
      float zg = zv2 + sc[u+512] * (float)sg;
      float zo = zv3 + sc[u+768] * (float)so;
      float c  = sigf(zf)*cst + sigf(zi)*tanh_(zg);
      float h  = sigf(zo)*tanh_(c);
      cst = c;
      int hqi = __float2int_rn(h * 127.0f);
      hqi = max(-127, min(127, hqi));
      ((signed char*)h8)[u] = (signed char)hqi;
      Y[row*256 + u] = h + rv;
    }
    // LDS-only fence: don't drain vmcnt; Y store drains under next step
    asm volatile("s_waitcnt lgkmcnt(0)\n\ts_barrier" ::: "memory");
  }
}

// ---- head: compact rnn_small (R8) ----
__global__ __launch_bounds__(256) void k_head(const float* __restrict__ Y4,
    const float* __restrict__ LWT,  // [256][256] f32 (linWT [f][u])
    const float* __restrict__ lb,
    const float* __restrict__ SWT,  // [256][28] f32  (scoreT [f][o])
    const float* __restrict__ sb,
    float* __restrict__ rnnS){      // [2730][28]
  __shared__ float v [8][256];
  __shared__ float h2[8][256];
  const int tid = threadIdx.x;
  const int m0 = blockIdx.x*8;
  for(int p=0;p<8;p++){
    int m = m0+p;
    v[p][tid] = (m<NM) ? Y4[m*256+tid] : 0.0f;
  }
  __syncthreads();
  float acc[8];
  float bz = lb[tid];
  #pragma unroll
  for(int p=0;p<8;p++) acc[p]=bz;
  #pragma unroll 4
  for(int f=0; f<256; f++){
    float w = LWT[f*256+tid];
    #pragma unroll
    for(int p=0;p<8;p++) acc[p] += w * v[p][f];
  }
  #pragma unroll
  for(int p=0;p<8;p++) h2[p][tid] = tanh_(acc[p]);
  __syncthreads();
  if(tid < 224){
    int o = tid % 28, p = tid / 28;
    int m = m0 + p;
    if(m < NM){
      float a = sb[o];
      for(int f=0; f<256; f++) a += SWT[f*28+o] * h2[p][f];
      rnnS[m*28 + o] = a;          // coalesced compact store
    }
  }
}

// ---- outs: rnn_out + prediction_values broadcast + holdout (coalesced) ----
__global__ __launch_bounds__(256) void k_outs(
    const float* __restrict__ rnnS, const float* __restrict__ ST,
    const float* __restrict__ lvlT, float* __restrict__ out){
  for(int i0 = blockIdx.x*256 + threadIdx.x; i0 < 978432 + 3584; i0 += 1024*256){
    int i = i0;
    if(i < 978432){                    // rnn_out (+ prediction_values)
      int t = i/3584; int rr = i - t*3584;
      int b = rr/28;  int o = rr - b*28;
      int j = b % 10;
      float a = rnnS[(t*10 + j)*28 + o];
      out[1759744 + i] = a;
      if(t < 245) out[i] = a;
    } else { i -= 978432;              // holdout_prediction
      int b = i/28, o = i - (i/28)*28;
      int j = b % 10;
      float a = rnnS[(2720 + j)*28 + o];
      int col = (o < 21) ? (286+o) : (279+o);
      float hv = a * ST[col*128 + b] * lvlT[299*128 + b];
      out[1756160 + i] = (hv > 0.0f) ? hv : 0.0f;
    }
  }
}

extern "C" void kernel_launch(void* const* d_in, const int* in_sizes, int n_in,
                              void* d_out, int out_size, void* d_ws, size_t ws_size,
                              hipStream_t stream){
  (void)in_sizes; (void)n_in; (void)out_size; (void)ws_size;
  const float* x     = (const float*)d_in[0];
  const float* val   = (const float*)d_in[1];
  const float* alpha = (const float*)d_in[2];
  const float* gamma = (const float*)d_in[3];
  const float* iseas = (const float*)d_in[4];
  const float* cats  = (const float*)d_in[5];
  const float* mp    = (const float*)d_in[6];
  const float* Wih[4]  = {(const float*)d_in[7],  (const float*)d_in[10], (const float*)d_in[13], (const float*)d_in[16]};
  const float* Whh[4]  = {(const float*)d_in[8],  (const float*)d_in[11], (const float*)d_in[14], (const float*)d_in[17]};
  const float* bias[4] = {(const float*)d_in[9],  (const float*)d_in[12], (const float*)d_in[15], (const float*)d_in[18]};
  const float* linW  = (const float*)d_in[19];
  const float* linb  = (const float*)d_in[20];
  const float* scW   = (const float*)d_in[21];
  const float* scb   = (const float*)d_in[22];

  // ---- workspace layout ----
  float* Fw   = (float*)d_ws;
  float* ST   = Fw;                 // 39296
  float* lvlT = ST   + 39296;       // 38400
  float* xT   = lvlT + 38400;       // 38400
  float* xz   = xT   + 38400;       // 2795520
  float* yA   = xz   + 2795520;     // 698880
  float* yB   = yA   + 698880;      // 698880
  float* wihT[4];
  wihT[0] = yB + 698880;            // 50176
  wihT[1] = wihT[0] + 50176;        // 262144
  wihT[2] = wihT[1] + 262144;
  wihT[3] = wihT[2] + 262144;
  float* linWT = wihT[3] + 262144;  // 65536
  float* scT   = linWT + 65536;     // 7168
  float* zsc   = scT   + 7168;      // 4096
  u32*   W8all = (u32*)(zsc + 4096);// 262144 u32
  float* rnnS  = (float*)(W8all + 262144); // 76440

  // ---- prep ----
  k_prep<<<3718, 256, 0, stream>>>(x, xT,
      Wih[0], wihT[0], Wih[1], wihT[1], Wih[2], wihT[2], Wih[3], wihT[3],
      linW, linWT, scW, scT,
      Whh[0], Whh[1], Whh[2], Whh[3], zsc);

  // ---- int8 pack + LDS-staged ES scan ----
  k_packes<<<1025, 256, 0, stream>>>(Whh[0], Whh[1], Whh[2], Whh[3], zsc, W8all,
                                     xT, alpha, gamma, iseas, ST, lvlT);

  // ---- 4 LSTM layers: Wih GEMM + scan (L1 scan carries piggyback) ----
  const int    dlt[4]    = {1, 2, 2, 6};
  const int    chains[4] = {10, 20, 20, 60};
  const float* Xin[4]    = {nullptr, yA, yB, yA};
  float*       Yout[4]   = {yA, yB, yA, yA};
  for(int l=0;l<4;l++){
    if(l == 0)
      k_gemm1<<<(NM+7)/8, 256, 0, stream>>>(xT, ST, lvlT, cats, mp,
                                            wihT[0], bias[0], xz);
    else
      k_gemm<<<(NM+7)/8, 256, 0, stream>>>(Xin[l], wihT[l], bias[l], xz);
    int grid = (l == 0) ? 256 : chains[l];   // L1: +246 piggyback blocks
    k_scan8<<<grid, 512, 0, stream>>>(xz, W8all + l*65536, zsc + l*1024,
                                      Yout[l],
                                      (l==3) ? yB : (const float*)nullptr,
                                      xT, ST, lvlT, val, (float*)d_out,
                                      chains[l], dlt[l]);
  }

  // ---- head (compact) + broadcast outs ----
  k_head<<<(NM+7)/8, 256, 0, stream>>>(yA, linWT, linb, scT, scb, rnnS);
  k_outs<<<1024, 256, 0, stream>>>(rnnS, ST, lvlT, (float*)d_out);
}